// Round 1
// baseline (548.235 us; speedup 1.0000x reference)
//
#include <hip/hip_runtime.h>
#include <cstdint>
#include <cstddef>

// ---------------------------------------------------------------------------
// BsPINN forward, f16 MFMA (round 12).
// R11 green: 490us. Hot GEMM: MfmaUtil 32 / VALUBusy 34 / occ 36 / HBM 27 —
// nothing saturated => 2-barrier drain-stall structure + LDS over-traffic.
// R12: 256x256 tile, BK=32, 4-deep circular LDS pipeline:
//   - global_load_lds width=16 staging (no VGPR round-trip, no staging VALU)
//   - stage tile t+3 while computing t; steady-state gate s_waitcnt vmcnt(8)
//     (counted, never 0) + ONE raw s_barrier per K-tile (no __syncthreads)
//   - LDS XOR swizzle (slot ^= (row>>1)&3) via pre-swizzled GLOBAL source
//     (linear LDS dest) + same involution on ds_read => <=2-way conflicts
//   - wave tile 128x64: 32 MFMA per barrier window vs 12 ds_read_b128
//   - s_setprio(1) around MFMA cluster; XCD-chunked swizzle, n-fast
// Epilogues unchanged from R11 (validated): bias+tanh store, or fused
// tanh . W_last dot -> shfl-reduce -> atomicAdd(out) with out pre-init b_last.
// ---------------------------------------------------------------------------

typedef _Float16  f16x8   __attribute__((ext_vector_type(8)));
typedef float     floatx4 __attribute__((ext_vector_type(4)));
typedef float     floatx8 __attribute__((ext_vector_type(8)));

__device__ __forceinline__ float tanh_fast(float x) {
    float e = __expf(2.0f * x);
    return 1.0f - 2.0f / (e + 1.0f);
}

__device__ __forceinline__ void gload16(const _Float16* g, _Float16* l) {
    __builtin_amdgcn_global_load_lds(
        (const __attribute__((address_space(1))) unsigned int*)g,
        (__attribute__((address_space(3))) unsigned int*)l, 16, 0, 0);
}

// ---------------------------------------------------------------------------
// Weight transpose + f16 convert: fp32 W[K=1024][N=1024] -> f16 Wt[N][K].
// ---------------------------------------------------------------------------
__global__ __launch_bounds__(256)
void transposeH(const float* __restrict__ W, _Float16* __restrict__ Wt) {
    __shared__ float tile[32][33];
    const int tx = threadIdx.x & 31;
    const int ty = threadIdx.x >> 5;     // 0..7
    #pragma unroll
    for (int j = 0; j < 4; ++j) {
        int r = ty + j * 8;
        tile[r][tx] = W[(size_t)(blockIdx.y * 32 + r) * 1024 + blockIdx.x * 32 + tx];
    }
    __syncthreads();
    #pragma unroll
    for (int j = 0; j < 4; ++j) {
        int r = ty + j * 8;
        Wt[(size_t)(blockIdx.x * 32 + r) * 1024 + blockIdx.y * 32 + tx] =
            (_Float16)tile[tx][r];
    }
}

// ---------------------------------------------------------------------------
// out[row] := b_last (fp32) — re-initialized every call before layer3 atomics.
// ---------------------------------------------------------------------------
__global__ __launch_bounds__(256)
void init_out(float* __restrict__ out, const float* __restrict__ bl) {
    out[blockIdx.x * 256 + threadIdx.x] = bl[0];
}

// ---------------------------------------------------------------------------
// Layer 0 (fp32 in): h0 = tanh(xa*W0[0][:] + xb*W0[1][:] + b0) -> f16.
// ---------------------------------------------------------------------------
__global__ __launch_bounds__(256)
void layer0_kernel(const float* __restrict__ X, const float* __restrict__ W0,
                   const float* __restrict__ b0, _Float16* __restrict__ H) {
    const int idx = blockIdx.x * 256 + threadIdx.x;
    const int row = idx >> 7;
    const int j0  = (idx & 127) << 3;
    const float x0 = X[row * 2 + 0];
    const float x1 = X[row * 2 + 1];
    const float xa = x0 * 0.31830988618379067f - 1.0f;   // x0/pi - 1
    const float xb = 2.0f * x1 - 1.0f;
    floatx8 wa = *(const floatx8*)(W0 + j0);
    floatx8 wb = *(const floatx8*)(W0 + 1024 + j0);
    floatx8 bb = *(const floatx8*)(b0 + j0);
    f16x8 o;
    #pragma unroll
    for (int j = 0; j < 8; ++j) {
        float v = fmaf(xa, wa[j], fmaf(xb, wb[j], bb[j]));
        o[j] = (_Float16)tanh_fast(v);
    }
    *(f16x8*)(H + (size_t)row * 1024 + j0) = o;
}

// ---------------------------------------------------------------------------
// GEMM + bias + tanh, f16. 256x256 tile, 512 threads = 8 waves (2m x 4n),
// each wave 128x64 via 8x4 16x16x32 frags (128 acc VGPR). BK=32.
// LDS: As[4][256*32], Bs[4][256*32] f16 = 128 KiB, 4-slot circular buffer.
// Pipeline: prologue stages tiles 0..2; iter t gates own loads of t with
// vmcnt(8) (tiles t+1,t+2 stay in flight), raw s_barrier, then stages t+3
// into slot (t-1)&3 (all waves provably past their reads of t-1), ds_reads
// tile t, 32 MFMA. Tail gates vmcnt(4)/vmcnt(0).
// Swizzle: 16B slot s within a 64B row stored at s ^ ((row>>1)&3); the
// global source address is pre-swizzled (involution), LDS dest is linear
// (global_load_lds requirement); ds_read applies the same XOR => 2-way max.
// KB = diag block: cols [n0,n0+256) need k in [(n0/KB)*KB, +KB).
// FUSE: per-row partial of tanh(pre) . Wl over this wave's 64 cols,
// shfl-reduce over 16 r-lanes, one fp32 atomic per row (out pre-init b_last).
// ---------------------------------------------------------------------------
template <bool FUSE>
__global__ __launch_bounds__(512, 2)
void gemm256(const _Float16* __restrict__ A, const _Float16* __restrict__ Bt,
             const float* __restrict__ bias, _Float16* __restrict__ C,
             const float* __restrict__ Wl, float* __restrict__ out, int KB) {
    __shared__ _Float16 As[4 * 8192];   // 64 KB
    __shared__ _Float16 Bs[4 * 8192];   // 64 KB

    const int tid  = threadIdx.x;
    const int lane = tid & 63;
    const int w    = tid >> 6;

    // grid: x = n (4, fast), y = m. XCD-chunked bijective swizzle so each
    // XCD gets contiguous m with all 4 n (A rows L2-resident per XCD).
    const int total = gridDim.x * gridDim.y;
    int lid = blockIdx.y * 4 + blockIdx.x;
    if ((total & 7) == 0) {
        const int qq = total >> 3;
        lid = (lid & 7) * qq + (lid >> 3);
    }
    const int n0 = (lid & 3) << 8;
    const int m0 = (lid >> 2) << 8;

    const int kbeg = (n0 / KB) * KB;
    const int NT   = KB >> 5;                 // K-tiles of 32

    // ---- staging addressing: 1024 16B-chunks per tile per matrix,
    // 2 A-chunks + 2 B-chunks per thread. chunk c -> row c>>2, phys slot c&3,
    // logical k-slot = (c&3) ^ ((row>>1)&3)  (pre-swizzled source).
    const int c0  = w * 128 + lane;
    const int c1  = c0 + 64;
    const int rw0 = c0 >> 2, sl0 = (c0 & 3) ^ ((rw0 >> 1) & 3);
    const int rw1 = c1 >> 2, sl1 = (c1 & 3) ^ ((rw1 >> 1) & 3);
    const _Float16* gA0 = A  + (size_t)(m0 + rw0) * 1024 + kbeg + sl0 * 8;
    const _Float16* gA1 = A  + (size_t)(m0 + rw1) * 1024 + kbeg + sl1 * 8;
    const _Float16* gB0 = Bt + (size_t)(n0 + rw0) * 1024 + kbeg + sl0 * 8;
    const _Float16* gB1 = Bt + (size_t)(n0 + rw1) * 1024 + kbeg + sl1 * 8;
    const int ldsC0 = c0 * 8, ldsC1 = c1 * 8;     // elem offsets (lane-linear)

    // ---- frag read addressing (same involution on the read side)
    const int r   = lane & 15, q = lane >> 4;
    const int swz = (q ^ ((r >> 1) & 3)) << 3;    // elem offset of 16B slot
    const int wm  = (w & 1) << 7;                 // 0 / 128
    const int wn  = (w >> 1) << 6;                // 0 / 64 / 128 / 192

    floatx4 acc[8][4];
    #pragma unroll
    for (int i = 0; i < 8; ++i)
        #pragma unroll
        for (int j = 0; j < 4; ++j)
            acc[i][j] = floatx4{0.f, 0.f, 0.f, 0.f};

#define STAGE(tt) do {                                        \
        const int _s  = ((tt) & 3) * 8192;                    \
        const int _ko = (tt) * 32;                            \
        gload16(gA0 + _ko, As + _s + ldsC0);                  \
        gload16(gA1 + _ko, As + _s + ldsC1);                  \
        gload16(gB0 + _ko, Bs + _s + ldsC0);                  \
        gload16(gB1 + _ko, Bs + _s + ldsC1);                  \
    } while (0)

    STAGE(0); STAGE(1); STAGE(2);                 // 12 loads in flight

    for (int t = 0; t < NT; ++t) {
        // gate: own loads of tile t landed; t+1,t+2 stay in flight (counted).
        if (t < NT - 2)       asm volatile("s_waitcnt vmcnt(8)" ::: "memory");
        else if (t == NT - 2) asm volatile("s_waitcnt vmcnt(4)" ::: "memory");
        else                  asm volatile("s_waitcnt vmcnt(0)" ::: "memory");
        __builtin_amdgcn_s_barrier();             // raw: no waitcnt drain
        asm volatile("" ::: "memory");

        if (t + 3 < NT) STAGE(t + 3);             // slot (t-1)&3: safe now

        const _Float16* At = As + (t & 3) * 8192;
        const _Float16* Bw = Bs + (t & 3) * 8192;
        f16x8 af[8], bf[4];
        #pragma unroll
        for (int i = 0; i < 8; ++i)
            af[i] = *(const f16x8*)(At + (wm + i * 16 + r) * 32 + swz);
        #pragma unroll
        for (int j = 0; j < 4; ++j)
            bf[j] = *(const f16x8*)(Bw + (wn + j * 16 + r) * 32 + swz);

        __builtin_amdgcn_s_setprio(1);
        #pragma unroll
        for (int i = 0; i < 8; ++i)
            #pragma unroll
            for (int j = 0; j < 4; ++j)
                acc[i][j] = __builtin_amdgcn_mfma_f32_16x16x32_f16(af[i], bf[j], acc[i][j], 0, 0, 0);
        __builtin_amdgcn_s_setprio(0);
    }
#undef STAGE

    // Epilogue. C/D layout: col=lane&15 (within 16), row=(lane>>4)*4+reg.
    float bv[4], wlv[4];
    #pragma unroll
    for (int j = 0; j < 4; ++j) {
        const int col = n0 + wn + j * 16 + r;
        bv[j] = bias[col];
        if (FUSE) wlv[j] = Wl[col];
    }
    #pragma unroll
    for (int i = 0; i < 8; ++i) {
        const int row0 = m0 + wm + i * 16 + q * 4;
        #pragma unroll
        for (int rr = 0; rr < 4; ++rr) {
            if (!FUSE) {
                #pragma unroll
                for (int j = 0; j < 4; ++j) {
                    float o = tanh_fast(acc[i][j][rr] + bv[j]);
                    const int col = n0 + wn + j * 16 + r;
                    C[(size_t)(row0 + rr) * 1024 + col] = (_Float16)o;
                }
            } else {
                float p = 0.f;
                #pragma unroll
                for (int j = 0; j < 4; ++j)
                    p = fmaf(tanh_fast(acc[i][j][rr] + bv[j]), wlv[j], p);
                p += __shfl_down(p, 8);
                p += __shfl_down(p, 4);
                p += __shfl_down(p, 2);
                p += __shfl_down(p, 1);
                if (r == 0) atomicAdd(out + row0 + rr, p);
            }
        }
    }
}

// ---------------------------------------------------------------------------
extern "C" void kernel_launch(void* const* d_in, const int* in_sizes, int n_in,
                              void* d_out, int out_size, void* d_ws, size_t ws_size,
                              hipStream_t stream) {
    const float* X  = (const float*)d_in[0];
    const float* W0 = (const float*)d_in[1];
    const float* b0 = (const float*)d_in[2];
    const float* W1 = (const float*)d_in[3];
    const float* b1 = (const float*)d_in[4];
    const float* W2 = (const float*)d_in[5];
    const float* b2 = (const float*)d_in[6];
    const float* W3 = (const float*)d_in[7];
    const float* b3 = (const float*)d_in[8];
    const float* Wl = (const float*)d_in[9];
    const float* bl = (const float*)d_in[10];
    float* out = (float*)d_out;

    const int Nrows = in_sizes[0] / 2;                 // 65536
    const size_t WT = 1024 * 1024;                     // elems per f16 weight plane
    const size_t wt_bytes = 3 * WT * 2;                // 6 MiB
    const size_t slack = 512;

    // chunk rows R (pow2, multiple of 256): 2 f16 planes must fit ws.
    int R = 0;
    const int Rcap = Nrows < 32768 ? Nrows : 32768;
    for (int r = Rcap; r >= 256; r >>= 1)
        if ((size_t)2 * r * 2048 + wt_bytes + slack <= ws_size) { R = r; break; }
    if (!R) return;

    _Float16* wsp = (_Float16*)d_ws;
    _Float16* Wt1 = wsp;
    _Float16* Wt2 = Wt1 + WT;
    _Float16* Wt3 = Wt2 + WT;
    const size_t plane = (size_t)R * 1024;
    _Float16* P0 = Wt3 + WT;
    _Float16* P1 = P0 + plane;

    const dim3 tb(256);
    transposeH<<<dim3(32, 32), tb, 0, stream>>>(W1, Wt1);
    transposeH<<<dim3(32, 32), tb, 0, stream>>>(W2, Wt2);
    transposeH<<<dim3(32, 32), tb, 0, stream>>>(W3, Wt3);
    init_out<<<Nrows / 256, tb, 0, stream>>>(out, bl);

    const int nchunks = Nrows / R;
    for (int c = 0; c < nchunks; ++c) {
        const float* Xc = X + (size_t)c * R * 2;
        float* outc = out + (size_t)c * R;

        layer0_kernel<<<R / 2, tb, 0, stream>>>(Xc, W0, b0, P0);

        const dim3 tg(512);
        const dim3 gg(4, R / 256);                    // n fast, xcd-chunked in-kernel
        gemm256<false><<<gg, tg, 0, stream>>>(P0, Wt1, b1, P1, nullptr, nullptr, 1024);
        gemm256<false><<<gg, tg, 0, stream>>>(P1, Wt2, b2, P0, nullptr, nullptr, 512);
        gemm256<true ><<<gg, tg, 0, stream>>>(P0, Wt3, b3, nullptr, Wl, outc, 256);
    }
}